// Round 5
// baseline (2012.688 us; speedup 1.0000x reference)
//
#include <hip/hip_runtime.h>
#include <hip/hip_bf16.h>

// Problem constants (fixed by the reference): B=8, S=2048, IN=4096, OUT=4096
#define M_TOT 16384
#define N_TOT 4096
#define K_TOT 4096
#define NELEM 16777216   // OUT*IN = 2^24 (index fits in 24 bits)

typedef __attribute__((ext_vector_type(8))) short bf16x8;
typedef __attribute__((ext_vector_type(4))) float f32x4;

#define AS1 __attribute__((address_space(1)))
#define AS3 __attribute__((address_space(3)))

struct SelState {
  unsigned long long prefix;   // accumulated high key bits
  unsigned long long thr;      // selection predicate: key <= thr
  unsigned int k_rem;
  unsigned int done;
  unsigned int active;
};

struct Ctl {
  unsigned long long pcount;   // mask popcount for dtype detection
  unsigned int mask_is_byte;
  unsigned int cand_n;         // compacted candidate count
  SelState d;                  // drop selection state
  SelState g;                  // grow selection state
};

__device__ Ctl g_ctl;
__device__ unsigned int g_hist[4096];
__device__ unsigned char g_elig[NELEM];          // 1 = slot OFF after drop (grow candidate)
__device__ unsigned short g_wb[NELEM];           // masked weight, bf16 bits [OUT][IN]
__device__ unsigned short g_xb[(size_t)M_TOT * K_TOT]; // x, bf16 bits [M][K]
__device__ unsigned long long g_cand[NELEM];     // compacted keys after radix pass 1

__device__ __forceinline__ unsigned short f2bf(float f) {
  unsigned int u = __float_as_uint(f);
  unsigned int r = (u + 0x7FFFu + ((u >> 16) & 1u)) >> 16;   // RNE
  return (unsigned short)r;
}

// 56-bit keys. Nonnegative floats: bit pattern order == value order.
__device__ __forceinline__ unsigned long long key_drop_bits(unsigned int fb, int i) {
  unsigned int b = fb & 0x7FFFFFFFu;
  return (((unsigned long long)b) << 24) | (unsigned int)i;   // smallest |w|, lowest idx first
}
__device__ __forceinline__ unsigned long long key_grow_bits(unsigned int fb, int i) {
  unsigned int b = ~(fb & 0x7FFFFFFFu);                       // descending |grad|
  return (((unsigned long long)b) << 24) | (unsigned int)i;   // largest |g|, lowest idx first
}

__global__ void ctl_reset() {
  int t = threadIdx.x;
  if (t == 0) { g_ctl.pcount = 0ull; g_ctl.cand_n = 0u; }
  for (int i = t; i < 4096; i += 256) g_hist[i] = 0;
}

// Detect mask dtype: read first NELEM bytes as u32 words (safe under both
// interpretations). bytes(bool): popcnt ~= 2.18M ; int32: popcnt ~= 545K.
__global__ void mask_popcnt(const unsigned int* mw) {
  const int NW = NELEM / 4;
  unsigned int s = 0;
  for (int i = blockIdx.x * blockDim.x + threadIdx.x; i < NW; i += gridDim.x * blockDim.x)
    s += __popc(mw[i]);
  for (int off = 32; off > 0; off >>= 1) s += __shfl_down(s, off, 64);
  if ((threadIdx.x & 63) == 0)
    atomicAdd((unsigned long long*)&g_ctl.pcount, (unsigned long long)s);
}

__global__ void sel_init(const int* ndp) {
  unsigned int k = (unsigned int)ndp[0];
  g_ctl.mask_is_byte = (g_ctl.pcount > 1200000ull) ? 1u : 0u;
  SelState s;
  s.prefix = 0ull; s.thr = 0ull; s.k_rem = k;
  s.done = (k == 0u) ? 1u : 0u;
  s.active = (k > 0u) ? 1u : 0u;
  g_ctl.d = s;
  g_ctl.g = s;
}

// Histogram of key bit-slice [shift, shift+nbits) over the FULL array (pass 1).
template <int SEL>
__global__ __launch_bounds__(256) void hist_pass(const float* __restrict__ src, int shift, int nbits) {
  SelState& st = SEL ? g_ctl.g : g_ctl.d;
  if (st.done) return;
  __shared__ unsigned int lh[4096];
  const int nb = 1 << nbits;
  for (int i = threadIdx.x; i < nb; i += blockDim.x) lh[i] = 0;
  __syncthreads();
  const unsigned long long pref = st.prefix;
  const int N4 = NELEM / 4;
  for (int q = blockIdx.x * blockDim.x + threadIdx.x; q < N4; q += gridDim.x * blockDim.x) {
    float4 v = ((const float4*)src)[q];
    float fv[4] = {v.x, v.y, v.z, v.w};
    unsigned char ev[4] = {1, 1, 1, 1};
    if (SEL) {
      uchar4 e4 = ((const uchar4*)g_elig)[q];
      ev[0] = e4.x; ev[1] = e4.y; ev[2] = e4.z; ev[3] = e4.w;
    }
#pragma unroll
    for (int j = 0; j < 4; ++j) {
      if (SEL && !ev[j]) continue;
      int i = q * 4 + j;
      unsigned int fb = __float_as_uint(fv[j]);
      unsigned long long key = SEL ? key_grow_bits(fb, i) : key_drop_bits(fb, i);
      if ((key >> (shift + nbits)) == pref)
        atomicAdd(&lh[(unsigned int)(key >> shift) & (unsigned int)(nb - 1)], 1u);
    }
  }
  __syncthreads();
  for (int i = threadIdx.x; i < nb; i += blockDim.x)
    if (lh[i]) atomicAdd(&g_hist[i], lh[i]);
}

// After pass 1: compact all keys matching the selected 12-bit prefix.
// Append order is nondeterministic but selection depends only on the
// multiset of keys -> deterministic result.
template <int SEL>
__global__ __launch_bounds__(256) void compact_pass(const float* __restrict__ src) {
  SelState& st = SEL ? g_ctl.g : g_ctl.d;
  if (st.done) return;
  const unsigned long long pref = st.prefix;   // 12 bits after pass 1
  const int N4 = NELEM / 4;
  for (int q = blockIdx.x * blockDim.x + threadIdx.x; q < N4; q += gridDim.x * blockDim.x) {
    float4 v = ((const float4*)src)[q];
    float fv[4] = {v.x, v.y, v.z, v.w};
    unsigned char ev[4] = {1, 1, 1, 1};
    if (SEL) {
      uchar4 e4 = ((const uchar4*)g_elig)[q];
      ev[0] = e4.x; ev[1] = e4.y; ev[2] = e4.z; ev[3] = e4.w;
    }
    unsigned long long keys[4]; int nk = 0;
#pragma unroll
    for (int j = 0; j < 4; ++j) {
      if (SEL && !ev[j]) continue;
      int i = q * 4 + j;
      unsigned int fb = __float_as_uint(fv[j]);
      unsigned long long key = SEL ? key_grow_bits(fb, i) : key_drop_bits(fb, i);
      if ((key >> 44) == pref) keys[nk++] = key;
    }
    if (nk) {
      unsigned int base = atomicAdd(&g_ctl.cand_n, (unsigned int)nk);
      for (int j = 0; j < nk; ++j) g_cand[base + j] = keys[j];
    }
  }
}

// Passes 2..5: histogram over compacted candidates only.
template <int SEL>
__global__ __launch_bounds__(256) void hist_cand(int shift, int nbits) {
  SelState& st = SEL ? g_ctl.g : g_ctl.d;
  if (st.done) return;
  __shared__ unsigned int lh[4096];
  const int nb = 1 << nbits;
  for (int i = threadIdx.x; i < nb; i += blockDim.x) lh[i] = 0;
  __syncthreads();
  const unsigned long long pref = st.prefix;
  const unsigned int n = g_ctl.cand_n;
  for (unsigned int i = blockIdx.x * blockDim.x + threadIdx.x; i < n; i += gridDim.x * blockDim.x) {
    unsigned long long key = g_cand[i];
    if ((key >> (shift + nbits)) == pref)
      atomicAdd(&lh[(unsigned int)(key >> shift) & (unsigned int)(nb - 1)], 1u);
  }
  __syncthreads();
  for (int i = threadIdx.x; i < nb; i += blockDim.x)
    if (lh[i]) atomicAdd(&g_hist[i], lh[i]);
}

// Single-block: find the bin containing the k_rem-th element, update state,
// zero the histogram for the next pass.
template <int SEL>
__global__ void select_pass(int shift, int nbits) {
  SelState& st = SEL ? g_ctl.g : g_ctl.d;
  if (st.done) return;   // hist untouched (stays zero) when done
  __shared__ unsigned int sc[256];
  __shared__ int tgt;
  const int nb = 1 << nbits;
  const int per = (nb + 255) / 256;
  const int t = threadIdx.x;
  unsigned int s = 0;
  for (int j = 0; j < per; ++j) {
    int b = t * per + j;
    if (b < nb) s += g_hist[b];
  }
  sc[t] = s;
  __syncthreads();
  for (int off = 1; off < 256; off <<= 1) {   // inclusive scan
    unsigned int v = (t >= off) ? sc[t - off] : 0u;
    __syncthreads();
    sc[t] += v;
    __syncthreads();
  }
  const unsigned int k = st.k_rem;
  const unsigned int cum = sc[t];
  const unsigned int before = cum - s;
  if (before < k && k <= cum) tgt = t;   // exactly one thread matches
  __syncthreads();
  if (t == tgt) {
    unsigned int c = before;
    for (int j = 0; j < per; ++j) {
      int b = t * per + j;
      unsigned int h = (b < nb) ? g_hist[b] : 0u;
      if (c + h >= k) {
        unsigned long long np = (st.prefix << nbits) | (unsigned long long)(unsigned int)b;
        st.prefix = np;
        st.k_rem = k - c;
        st.thr = ((np + 1ull) << shift) - 1ull;   // all keys with this prefix or less
        if (k - c == h) st.done = 1;              // k-th is the max of this bin: exact
        break;
      }
      c += h;
    }
  }
  __syncthreads();
  for (int b = t; b < nb; b += 256) g_hist[b] = 0;
}

// eligible (grow candidate) = slot OFF after drop = !mask || dropped. 4/thread.
// Also resets cand_n for the grow-phase compaction (stream-ordered).
__global__ __launch_bounds__(256) void build_elig(const float* __restrict__ w, const void* maskp) {
  if (blockIdx.x == 0 && threadIdx.x == 0) g_ctl.cand_n = 0u;
  int q = blockIdx.x * blockDim.x + threadIdx.x;   // over quads
  if (q >= NELEM / 4) return;
  float4 wv = ((const float4*)w)[q];
  float fv[4] = {wv.x, wv.y, wv.z, wv.w};
  unsigned char m[4];
  if (g_ctl.mask_is_byte) {
    uchar4 m4 = ((const uchar4*)maskp)[q];
    m[0] = m4.x; m[1] = m4.y; m[2] = m4.z; m[3] = m4.w;
  } else {
    int4 m4 = ((const int4*)maskp)[q];
    m[0] = m4.x != 0; m[1] = m4.y != 0; m[2] = m4.z != 0; m[3] = m4.w != 0;
  }
  const bool act = g_ctl.d.active;
  const unsigned long long thr = g_ctl.d.thr;
  uchar4 e;
  unsigned char ev[4];
#pragma unroll
  for (int j = 0; j < 4; ++j) {
    int i = q * 4 + j;
    bool dropped = act && (key_drop_bits(__float_as_uint(fv[j]), i) <= thr);
    ev[j] = (!m[j] || dropped) ? 1 : 0;
  }
  e.x = ev[0]; e.y = ev[1]; e.z = ev[2]; e.w = ev[3];
  ((uchar4*)g_elig)[q] = e;
}

// final mask: kept (= !elig) OR grown (elig && grow-key selected); emit bf16 W
__global__ __launch_bounds__(256) void build_wb(const float* __restrict__ w, const float* __restrict__ gr) {
  int q = blockIdx.x * blockDim.x + threadIdx.x;
  if (q >= NELEM / 4) return;
  float4 wv = ((const float4*)w)[q];
  float4 gv = ((const float4*)gr)[q];
  float wf[4] = {wv.x, wv.y, wv.z, wv.w};
  float gf[4] = {gv.x, gv.y, gv.z, gv.w};
  uchar4 e4 = ((const uchar4*)g_elig)[q];
  unsigned char ev[4] = {e4.x, e4.y, e4.z, e4.w};
  const bool act = g_ctl.g.active;
  const unsigned long long thr = g_ctl.g.thr;
  ushort4 o;
  unsigned short ov[4];
#pragma unroll
  for (int j = 0; j < 4; ++j) {
    int i = q * 4 + j;
    bool keep;
    if (!ev[j]) keep = true;
    else keep = act && (key_grow_bits(__float_as_uint(gf[j]), i) <= thr);
    ov[j] = keep ? f2bf(wf[j]) : (unsigned short)0;
  }
  o.x = ov[0]; o.y = ov[1]; o.z = ov[2]; o.w = ov[3];
  ((ushort4*)g_wb)[q] = o;
}

__global__ __launch_bounds__(256) void convert_x(const float* __restrict__ x) {
  int i = blockIdx.x * blockDim.x + threadIdx.x;   // over float4 quads
  float4 v = ((const float4*)x)[i];
  ushort4 o;
  o.x = f2bf(v.x); o.y = f2bf(v.y); o.z = f2bf(v.z); o.w = f2bf(v.w);
  ((ushort4*)g_xb)[i] = o;
}

// ---- GEMM: C[m][n] = sum_k X[m][k] * W[n][k], bf16 in, fp32 out ----
// 256x256 tile, BK=64, 512 threads = 8 waves (2M x 4N), per-wave 128x64 out.
//
// Read layout per K-tile (4 phases): ph1 reads A-quad0 + BOTH B halves
// (16 ds_reads), ph2 none, ph3 reads A-quad1 (8 ds_reads), ph4 none.
// MFMA walk q00,q01,q11,q10 (pB0/pB1 persist; pA reloaded at ph3).
// => per-tile last reads: B at ph1, A at ph3.
// Free times: buf0.B from ph2, buf0.A from ph4, buf1.B from ph6, buf1.A ph8.
//
// Stage slots (all strictly after target's last read + barrier):
//   ph1: T+1.A1   ph2: T+2.B0   ph3: T+2.B1   ph4: T+2.A0 + vm6
//   ph5: T+2.A1   ph6: T+3.B0   ph7: T+3.B1   ph8: T+3.A0 + vm6
// (T+1.A1's partner T+1.A0 staged at prev ph8; T+1.B at prev ph6/ph7.)
//
// vmcnt ledger (2 loads/stage): at ph4-wait in-flight = {prev s6,s7,s8,
// s1..s4} = 7 stages; retire through s1 (T+1.A1, so ALL of tile T+1) leaves
// {s2,s3,s4} = 6 loads -> vmcnt(6). Symmetric at ph8 (retire through T+2.A1,
// leaves {T+3.B0,B1,A0}). Binding issue->wait distance = 3 phases.
// Round-4's race (staging A halves while still being read) is gone: every
// slot's target region is past its last read with >=1 barrier between.
#define BM2 256
#define BN2 256
#define BK2 64
#define NT2 (K_TOT / BK2)      // 64 K-tiles
#define BUFB (256 * 128)       // LDS bytes per buffer (256 rows x 128B)

__global__ __launch_bounds__(512, 2) void gemm_kernel(float* __restrict__ out) {
  __shared__ unsigned short As[2][BM2][BK2];   // 64 KB
  __shared__ unsigned short Bs[2][BN2][BK2];   // 64 KB
  const int tid = threadIdx.x;
  const int lane = tid & 63;
  const int w = tid >> 6;            // 0..7
  const int wm = w >> 2, wn = w & 3;

  // XCD-aware swizzle: 1024 blocks, 8 XCDs, chunk = 128 (bijective, 1024%8==0)
  const int orig = blockIdx.x;
  const int swz = (orig & 7) * 128 + (orig >> 3);
  const int gm0 = (swz >> 4) * BM2;  // 64 M-tiles
  const int gn0 = (swz & 15) * BN2;  // 16 N-tiles

  f32x4 acc[8][4];
#pragma unroll
  for (int i = 0; i < 8; ++i)
#pragma unroll
    for (int j = 0; j < 4; ++j) acc[i][j] = (f32x4){0.f, 0.f, 0.f, 0.f};

  // ---- staging addressing (pre-swizzled global source, linear LDS dest) ----
  const int sr = (w << 3) + (lane >> 3);           // row 0..63 within a call
  const int sc = 8 * ((lane & 7) ^ (lane >> 3));   // swizzled source col (elems)
  const unsigned short* Agp = g_xb + (size_t)(gm0 + sr) * K_TOT + sc;
  const unsigned short* Bgp = g_wb + (size_t)(gn0 + sr) * K_TOT + sc;
  const int lr = (w << 3);                          // wave-uniform LDS row base

#define STAGE_A(tile, half) do {                                             \
    const int bi_ = (tile) & 1; const int kb_ = ((tile) & (NT2 - 1)) * BK2;  \
    __builtin_amdgcn_global_load_lds(                                        \
        (const AS1 void*)(Agp + (size_t)((half) * 128) * K_TOT + kb_),       \
        (AS3 void*)(&As[bi_][(half) * 128 + lr][0]), 16, 0, 0);              \
    __builtin_amdgcn_global_load_lds(                                        \
        (const AS1 void*)(Agp + (size_t)((half) * 128 + 64) * K_TOT + kb_),  \
        (AS3 void*)(&As[bi_][(half) * 128 + 64 + lr][0]), 16, 0, 0);         \
  } while (0)
#define STAGE_B(tile, half) do {                                             \
    const int bi_ = (tile) & 1; const int kb_ = ((tile) & (NT2 - 1)) * BK2;  \
    __builtin_amdgcn_global_load_lds(                                        \
        (const AS1 void*)(Bgp + (size_t)((half) * 128) * K_TOT + kb_),       \
        (AS3 void*)(&Bs[bi_][(half) * 128 + lr][0]), 16, 0, 0);              \
    __builtin_amdgcn_global_load_lds(                                        \
        (const AS1 void*)(Bgp + (size_t)((half) * 128 + 64) * K_TOT + kb_),  \
        (AS3 void*)(&Bs[bi_][(half) * 128 + 64 + lr][0]), 16, 0, 0);         \
  } while (0)

  // ---- fragment read addressing (XOR swizzle on byte column) ----
  const int r16 = lane & 15;
  const int kcb = (lane >> 4) << 4;        // 16B slot within 64B k-half
  const int xv = (r16 & 7) << 4;
  const char* Ab0 = (const char*)&As[0][wm * 128][0];
  const char* Bb0 = (const char*)&Bs[0][wn * 64][0];

  bf16x8 pA[4][2], pB0[2][2], pB1[2][2];

#define LD_A(qm, bi) do {                                                     \
    const char* ab_ = Ab0 + (bi) * BUFB + ((qm) * 64 + r16) * 128;            \
    _Pragma("unroll") for (int mi = 0; mi < 4; ++mi)                          \
      _Pragma("unroll") for (int sk = 0; sk < 2; ++sk)                        \
        pA[mi][sk] = *(const bf16x8*)(ab_ + mi * 16 * 128 +                   \
                                      ((sk * 64 + kcb) ^ xv));                \
  } while (0)
#define LD_B(P, qn, bi) do {                                                  \
    const char* bb_ = Bb0 + (bi) * BUFB + ((qn) * 32 + r16) * 128;            \
    _Pragma("unroll") for (int nf = 0; nf < 2; ++nf)                          \
      _Pragma("unroll") for (int sk = 0; sk < 2; ++sk)                        \
        P[nf][sk] = *(const bf16x8*)(bb_ + nf * 16 * 128 +                    \
                                     ((sk * 64 + kcb) ^ xv));                 \
  } while (0)
#define MFMA_Q(qm, qn, P) do {                                                \
    __builtin_amdgcn_s_setprio(1);                                            \
    _Pragma("unroll") for (int mi = 0; mi < 4; ++mi)                          \
      _Pragma("unroll") for (int nf = 0; nf < 2; ++nf)                        \
        _Pragma("unroll") for (int sk = 0; sk < 2; ++sk)                      \
          acc[(qm) * 4 + mi][(qn) * 2 + nf] =                                 \
              __builtin_amdgcn_mfma_f32_16x16x32_bf16(                        \
                  pA[mi][sk], P[nf][sk], acc[(qm) * 4 + mi][(qn) * 2 + nf],   \
                  0, 0, 0);                                                   \
    __builtin_amdgcn_s_setprio(0);                                            \
  } while (0)
#define BAR() __builtin_amdgcn_s_barrier()
#define WLG() asm volatile("s_waitcnt lgkmcnt(0)" ::: "memory")
#define WVM6() asm volatile("s_waitcnt vmcnt(6)" ::: "memory")

  // prologue: tile0 complete (4 stages), then T1.{B0,B1,A0} (3 stages);
  // vmcnt(6) retires exactly tile0 -> loop enters in steady-state invariant:
  // tile0 readable, {T1.B0,T1.B1,T1.A0} in flight, T1.A1 staged at ph1.
  STAGE_A(0, 0); STAGE_A(0, 1); STAGE_B(0, 0); STAGE_B(0, 1);
  STAGE_B(1, 0); STAGE_B(1, 1); STAGE_A(1, 0);
  WVM6();
  BAR();

  for (int it = 0; it < NT2 / 2; ++it) {
    const int T = 2 * it;
    // ---- K-tile T (buf0) ----
    // ph1: A-quad0 + both B halves (16 ds_reads)
    LD_A(0, 0); LD_B(pB0, 0, 0); LD_B(pB1, 1, 0);
    STAGE_A(T + 1, 1);
    BAR(); WLG();
    MFMA_Q(0, 0, pB0);
    BAR();
    // ph2: no ds_reads (pA, pB1 already live)
    STAGE_B(T + 2, 0);
    BAR();
    MFMA_Q(0, 1, pB1);
    BAR();
    // ph3: A-quad1 (8 ds_reads)
    LD_A(1, 0);
    STAGE_B(T + 2, 1);
    BAR(); WLG();
    MFMA_Q(1, 1, pB1);
    BAR();
    // ph4: vmcnt(6) after MFMA -> tile T+1 fully landed; {T2.B0,B1,A0} in flight
    STAGE_A(T + 2, 0);
    BAR();
    MFMA_Q(1, 0, pB0);
    WVM6();
    BAR();
    // ---- K-tile T+1 (buf1) ----
    // ph5
    LD_A(0, 1); LD_B(pB0, 0, 1); LD_B(pB1, 1, 1);
    STAGE_A(T + 2, 1);
    BAR(); WLG();
    MFMA_Q(0, 0, pB0);
    BAR();
    // ph6
    STAGE_B(T + 3, 0);
    BAR();
    MFMA_Q(0, 1, pB1);
    BAR();
    // ph7
    LD_A(1, 1);
    STAGE_B(T + 3, 1);
    BAR(); WLG();
    MFMA_Q(1, 1, pB1);
    BAR();
    // ph8: vmcnt(6) -> tile T+2 fully landed; {T3.B0,B1,A0} in flight
    STAGE_A(T + 3, 0);
    BAR();
    MFMA_Q(1, 0, pB0);
    WVM6();
    BAR();
  }

  // C/D layout (m89-verified): col = lane&15, row = (lane>>4)*4 + reg.
  const int cm0 = gm0 + wm * 128 + (lane >> 4) * 4;
  const int cn0 = gn0 + wn * 64 + (lane & 15);
#pragma unroll
  for (int mi = 0; mi < 8; ++mi)
#pragma unroll
    for (int nf = 0; nf < 4; ++nf)
#pragma unroll
      for (int r = 0; r < 4; ++r)
        out[(size_t)(cm0 + mi * 16 + r) * N_TOT + cn0 + nf * 16] = acc[mi][nf][r];
}

extern "C" void kernel_launch(void* const* d_in, const int* in_sizes, int n_in,
                              void* d_out, int out_size, void* d_ws, size_t ws_size,
                              hipStream_t stream) {
  const float* x  = (const float*)d_in[0];
  const float* wt = (const float*)d_in[1];
  const float* gr = (const float*)d_in[2];
  const void*  mk = d_in[3];
  const int*   nd = (const int*)d_in[4];
  (void)d_ws; (void)ws_size; (void)in_sizes; (void)n_in; (void)out_size;

  ctl_reset<<<1, 256, 0, stream>>>();
  mask_popcnt<<<512, 256, 0, stream>>>((const unsigned int*)mk);
  sel_init<<<1, 1, 0, stream>>>(nd);

  const int shifts[5] = {44, 32, 24, 12, 0};
  const int nbits[5]  = {12, 12, 8, 12, 12};

  // drop: k smallest |w| (global). Pass 1 full scan, then compact + 4 passes
  // over candidates only.
  hist_pass<0><<<1024, 256, 0, stream>>>(wt, shifts[0], nbits[0]);
  select_pass<0><<<1, 256, 0, stream>>>(shifts[0], nbits[0]);
  compact_pass<0><<<1024, 256, 0, stream>>>(wt);
  for (int p = 1; p < 5; ++p) {
    hist_cand<0><<<256, 256, 0, stream>>>(shifts[p], nbits[p]);
    select_pass<0><<<1, 256, 0, stream>>>(shifts[p], nbits[p]);
  }
  build_elig<<<NELEM / 4 / 256, 256, 0, stream>>>(wt, mk);
  // grow: k largest |grad| among eligible.
  hist_pass<1><<<1024, 256, 0, stream>>>(gr, shifts[0], nbits[0]);
  select_pass<1><<<1, 256, 0, stream>>>(shifts[0], nbits[0]);
  compact_pass<1><<<1024, 256, 0, stream>>>(gr);
  for (int p = 1; p < 5; ++p) {
    hist_cand<1><<<256, 256, 0, stream>>>(shifts[p], nbits[p]);
    select_pass<1><<<1, 256, 0, stream>>>(shifts[p], nbits[p]);
  }
  build_wb<<<NELEM / 4 / 256, 256, 0, stream>>>(wt, gr);
  convert_x<<<(M_TOT * K_TOT / 4) / 256, 256, 0, stream>>>(x);
  gemm_kernel<<<1024, 512, 0, stream>>>((float*)d_out);
}

// Round 6
// 1011.149 us; speedup vs baseline: 1.9905x; 1.9905x over previous
//
#include <hip/hip_runtime.h>
#include <hip/hip_bf16.h>

// Problem constants (fixed by the reference): B=8, S=2048, IN=4096, OUT=4096
#define M_TOT 16384
#define N_TOT 4096
#define K_TOT 4096
#define NELEM 16777216   // OUT*IN = 2^24 (index fits in 24 bits)

typedef __attribute__((ext_vector_type(8))) short bf16x8;
typedef __attribute__((ext_vector_type(4))) float f32x4;

#define AS1 __attribute__((address_space(1)))
#define AS3 __attribute__((address_space(3)))

struct SelState {
  unsigned long long prefix;   // accumulated high key bits
  unsigned long long thr;      // selection predicate: key <= thr
  unsigned int k_rem;
  unsigned int done;
  unsigned int active;
};

struct Ctl {
  unsigned long long pcount;   // mask popcount for dtype detection
  unsigned int mask_is_byte;
  unsigned int cand_n;         // compacted candidate count
  SelState d;                  // drop selection state
  SelState g;                  // grow selection state
};

__device__ Ctl g_ctl;
__device__ unsigned int g_hist[4096];
__device__ unsigned char g_elig[NELEM];          // 1 = slot OFF after drop (grow candidate)
__device__ unsigned short g_wb[NELEM];           // masked weight, bf16 bits [OUT][IN]
__device__ unsigned short g_xb[(size_t)M_TOT * K_TOT]; // x, bf16 bits [M][K]
__device__ unsigned long long g_cand[NELEM];     // compacted keys after radix pass 1

__device__ __forceinline__ unsigned short f2bf(float f) {
  unsigned int u = __float_as_uint(f);
  unsigned int r = (u + 0x7FFFu + ((u >> 16) & 1u)) >> 16;   // RNE
  return (unsigned short)r;
}

// 56-bit keys. Nonnegative floats: bit pattern order == value order.
__device__ __forceinline__ unsigned long long key_drop_bits(unsigned int fb, int i) {
  unsigned int b = fb & 0x7FFFFFFFu;
  return (((unsigned long long)b) << 24) | (unsigned int)i;   // smallest |w|, lowest idx first
}
__device__ __forceinline__ unsigned long long key_grow_bits(unsigned int fb, int i) {
  unsigned int b = ~(fb & 0x7FFFFFFFu);                       // descending |grad|
  return (((unsigned long long)b) << 24) | (unsigned int)i;   // largest |g|, lowest idx first
}

__global__ void ctl_reset() {
  int t = threadIdx.x;
  if (t == 0) { g_ctl.pcount = 0ull; g_ctl.cand_n = 0u; }
  for (int i = t; i < 4096; i += 256) g_hist[i] = 0;
}

// Detect mask dtype: read first NELEM bytes as u32 words (safe under both
// interpretations). bytes(bool): popcnt ~= 2.18M ; int32: popcnt ~= 545K.
__global__ void mask_popcnt(const unsigned int* mw) {
  const int NW = NELEM / 4;
  unsigned int s = 0;
  for (int i = blockIdx.x * blockDim.x + threadIdx.x; i < NW; i += gridDim.x * blockDim.x)
    s += __popc(mw[i]);
  for (int off = 32; off > 0; off >>= 1) s += __shfl_down(s, off, 64);
  if ((threadIdx.x & 63) == 0)
    atomicAdd((unsigned long long*)&g_ctl.pcount, (unsigned long long)s);
}

__global__ void sel_init(const int* ndp) {
  unsigned int k = (unsigned int)ndp[0];
  g_ctl.mask_is_byte = (g_ctl.pcount > 1200000ull) ? 1u : 0u;
  SelState s;
  s.prefix = 0ull; s.thr = 0ull; s.k_rem = k;
  s.done = (k == 0u) ? 1u : 0u;
  s.active = (k > 0u) ? 1u : 0u;
  g_ctl.d = s;
  g_ctl.g = s;
}

// Histogram of key bit-slice [shift, shift+nbits) over the FULL array (pass 1).
template <int SEL>
__global__ __launch_bounds__(256) void hist_pass(const float* __restrict__ src, int shift, int nbits) {
  SelState& st = SEL ? g_ctl.g : g_ctl.d;
  if (st.done) return;
  __shared__ unsigned int lh[4096];
  const int nb = 1 << nbits;
  for (int i = threadIdx.x; i < nb; i += blockDim.x) lh[i] = 0;
  __syncthreads();
  const unsigned long long pref = st.prefix;
  const int N4 = NELEM / 4;
  for (int q = blockIdx.x * blockDim.x + threadIdx.x; q < N4; q += gridDim.x * blockDim.x) {
    float4 v = ((const float4*)src)[q];
    float fv[4] = {v.x, v.y, v.z, v.w};
    unsigned char ev[4] = {1, 1, 1, 1};
    if (SEL) {
      uchar4 e4 = ((const uchar4*)g_elig)[q];
      ev[0] = e4.x; ev[1] = e4.y; ev[2] = e4.z; ev[3] = e4.w;
    }
#pragma unroll
    for (int j = 0; j < 4; ++j) {
      if (SEL && !ev[j]) continue;
      int i = q * 4 + j;
      unsigned int fb = __float_as_uint(fv[j]);
      unsigned long long key = SEL ? key_grow_bits(fb, i) : key_drop_bits(fb, i);
      if ((key >> (shift + nbits)) == pref)
        atomicAdd(&lh[(unsigned int)(key >> shift) & (unsigned int)(nb - 1)], 1u);
    }
  }
  __syncthreads();
  for (int i = threadIdx.x; i < nb; i += blockDim.x)
    if (lh[i]) atomicAdd(&g_hist[i], lh[i]);
}

// After pass 1: compact keys matching the selected 12-bit prefix.
// Hierarchical append (G12): matches -> per-block LDS buffer (LDS atomics,
// ~tens per block), then ONE global atomicAdd per block reserves a contiguous
// range and the buffer is copied out coalesced. 1024 global atomics total
// instead of one per match (round-5's 738us single-address serialization).
// Overflow (slot >= CCAP, never expected at ~60 matches/block vs cap 4096):
// direct append reserving from the same counter -> multiset still exact,
// selection (histogram-based) is order-independent -> deterministic result.
#define CCAP 4096
template <int SEL>
__global__ __launch_bounds__(256) void compact_pass(const float* __restrict__ src) {
  SelState& st = SEL ? g_ctl.g : g_ctl.d;
  if (st.done) return;
  __shared__ unsigned long long lk[CCAP];   // 32 KB
  __shared__ unsigned int ln;
  __shared__ unsigned int gbase;
  if (threadIdx.x == 0) ln = 0;
  __syncthreads();
  const unsigned long long pref = st.prefix;   // 12 bits after pass 1
  const int N4 = NELEM / 4;
  for (int q = blockIdx.x * blockDim.x + threadIdx.x; q < N4; q += gridDim.x * blockDim.x) {
    float4 v = ((const float4*)src)[q];
    float fv[4] = {v.x, v.y, v.z, v.w};
    unsigned char ev[4] = {1, 1, 1, 1};
    if (SEL) {
      uchar4 e4 = ((const uchar4*)g_elig)[q];
      ev[0] = e4.x; ev[1] = e4.y; ev[2] = e4.z; ev[3] = e4.w;
    }
#pragma unroll
    for (int j = 0; j < 4; ++j) {
      if (SEL && !ev[j]) continue;
      int i = q * 4 + j;
      unsigned int fb = __float_as_uint(fv[j]);
      unsigned long long key = SEL ? key_grow_bits(fb, i) : key_drop_bits(fb, i);
      if ((key >> 44) == pref) {
        unsigned int slot = atomicAdd(&ln, 1u);
        if (slot < CCAP) {
          lk[slot] = key;
        } else {                               // overflow fallback (cold)
          unsigned int gb = atomicAdd(&g_ctl.cand_n, 1u);
          g_cand[gb] = key;
        }
      }
    }
  }
  __syncthreads();
  unsigned int n = ln < CCAP ? ln : CCAP;
  if (threadIdx.x == 0) gbase = atomicAdd(&g_ctl.cand_n, n);
  __syncthreads();
  for (unsigned int i = threadIdx.x; i < n; i += blockDim.x)
    g_cand[gbase + i] = lk[i];
}

// Passes 2..5: histogram over compacted candidates only.
template <int SEL>
__global__ __launch_bounds__(256) void hist_cand(int shift, int nbits) {
  SelState& st = SEL ? g_ctl.g : g_ctl.d;
  if (st.done) return;
  __shared__ unsigned int lh[4096];
  const int nb = 1 << nbits;
  for (int i = threadIdx.x; i < nb; i += blockDim.x) lh[i] = 0;
  __syncthreads();
  const unsigned long long pref = st.prefix;
  const unsigned int n = g_ctl.cand_n;
  for (unsigned int i = blockIdx.x * blockDim.x + threadIdx.x; i < n; i += gridDim.x * blockDim.x) {
    unsigned long long key = g_cand[i];
    if ((key >> (shift + nbits)) == pref)
      atomicAdd(&lh[(unsigned int)(key >> shift) & (unsigned int)(nb - 1)], 1u);
  }
  __syncthreads();
  for (int i = threadIdx.x; i < nb; i += blockDim.x)
    if (lh[i]) atomicAdd(&g_hist[i], lh[i]);
}

// Single-block: find the bin containing the k_rem-th element, update state,
// zero the histogram for the next pass.
template <int SEL>
__global__ void select_pass(int shift, int nbits) {
  SelState& st = SEL ? g_ctl.g : g_ctl.d;
  if (st.done) return;   // hist untouched (stays zero) when done
  __shared__ unsigned int sc[256];
  __shared__ int tgt;
  const int nb = 1 << nbits;
  const int per = (nb + 255) / 256;
  const int t = threadIdx.x;
  unsigned int s = 0;
  for (int j = 0; j < per; ++j) {
    int b = t * per + j;
    if (b < nb) s += g_hist[b];
  }
  sc[t] = s;
  __syncthreads();
  for (int off = 1; off < 256; off <<= 1) {   // inclusive scan
    unsigned int v = (t >= off) ? sc[t - off] : 0u;
    __syncthreads();
    sc[t] += v;
    __syncthreads();
  }
  const unsigned int k = st.k_rem;
  const unsigned int cum = sc[t];
  const unsigned int before = cum - s;
  if (before < k && k <= cum) tgt = t;   // exactly one thread matches
  __syncthreads();
  if (t == tgt) {
    unsigned int c = before;
    for (int j = 0; j < per; ++j) {
      int b = t * per + j;
      unsigned int h = (b < nb) ? g_hist[b] : 0u;
      if (c + h >= k) {
        unsigned long long np = (st.prefix << nbits) | (unsigned long long)(unsigned int)b;
        st.prefix = np;
        st.k_rem = k - c;
        st.thr = ((np + 1ull) << shift) - 1ull;   // all keys with this prefix or less
        if (k - c == h) st.done = 1;              // k-th is the max of this bin: exact
        break;
      }
      c += h;
    }
  }
  __syncthreads();
  for (int b = t; b < nb; b += 256) g_hist[b] = 0;
}

// eligible (grow candidate) = slot OFF after drop = !mask || dropped. 4/thread.
// Also resets cand_n for the grow-phase compaction (stream-ordered).
__global__ __launch_bounds__(256) void build_elig(const float* __restrict__ w, const void* maskp) {
  if (blockIdx.x == 0 && threadIdx.x == 0) g_ctl.cand_n = 0u;
  int q = blockIdx.x * blockDim.x + threadIdx.x;   // over quads
  if (q >= NELEM / 4) return;
  float4 wv = ((const float4*)w)[q];
  float fv[4] = {wv.x, wv.y, wv.z, wv.w};
  unsigned char m[4];
  if (g_ctl.mask_is_byte) {
    uchar4 m4 = ((const uchar4*)maskp)[q];
    m[0] = m4.x; m[1] = m4.y; m[2] = m4.z; m[3] = m4.w;
  } else {
    int4 m4 = ((const int4*)maskp)[q];
    m[0] = m4.x != 0; m[1] = m4.y != 0; m[2] = m4.z != 0; m[3] = m4.w != 0;
  }
  const bool act = g_ctl.d.active;
  const unsigned long long thr = g_ctl.d.thr;
  uchar4 e;
  unsigned char ev[4];
#pragma unroll
  for (int j = 0; j < 4; ++j) {
    int i = q * 4 + j;
    bool dropped = act && (key_drop_bits(__float_as_uint(fv[j]), i) <= thr);
    ev[j] = (!m[j] || dropped) ? 1 : 0;
  }
  e.x = ev[0]; e.y = ev[1]; e.z = ev[2]; e.w = ev[3];
  ((uchar4*)g_elig)[q] = e;
}

// final mask: kept (= !elig) OR grown (elig && grow-key selected); emit bf16 W
__global__ __launch_bounds__(256) void build_wb(const float* __restrict__ w, const float* __restrict__ gr) {
  int q = blockIdx.x * blockDim.x + threadIdx.x;
  if (q >= NELEM / 4) return;
  float4 wv = ((const float4*)w)[q];
  float4 gv = ((const float4*)gr)[q];
  float wf[4] = {wv.x, wv.y, wv.z, wv.w};
  float gf[4] = {gv.x, gv.y, gv.z, gv.w};
  uchar4 e4 = ((const uchar4*)g_elig)[q];
  unsigned char ev[4] = {e4.x, e4.y, e4.z, e4.w};
  const bool act = g_ctl.g.active;
  const unsigned long long thr = g_ctl.g.thr;
  ushort4 o;
  unsigned short ov[4];
#pragma unroll
  for (int j = 0; j < 4; ++j) {
    int i = q * 4 + j;
    bool keep;
    if (!ev[j]) keep = true;
    else keep = act && (key_grow_bits(__float_as_uint(gf[j]), i) <= thr);
    ov[j] = keep ? f2bf(wf[j]) : (unsigned short)0;
  }
  o.x = ov[0]; o.y = ov[1]; o.z = ov[2]; o.w = ov[3];
  ((ushort4*)g_wb)[q] = o;
}

__global__ __launch_bounds__(256) void convert_x(const float* __restrict__ x) {
  int i = blockIdx.x * blockDim.x + threadIdx.x;   // over float4 quads
  float4 v = ((const float4*)x)[i];
  ushort4 o;
  o.x = f2bf(v.x); o.y = f2bf(v.y); o.z = f2bf(v.z); o.w = f2bf(v.w);
  ((ushort4*)g_xb)[i] = o;
}

// ---- GEMM: C[m][n] = sum_k X[m][k] * W[n][k], bf16 in, fp32 out ----
// 256x256 tile, BK=64, 512 threads = 8 waves (2M x 4N), per-wave 128x64 out.
// (UNCHANGED from round 5 — verified correct, vmcnt(6) ledger.)
//
// Read layout per K-tile (4 phases): ph1 reads A-quad0 + BOTH B halves
// (16 ds_reads), ph2 none, ph3 reads A-quad1 (8 ds_reads), ph4 none.
// MFMA walk q00,q01,q11,q10 (pB0/pB1 persist; pA reloaded at ph3).
// => per-tile last reads: B at ph1, A at ph3.
// Free times: buf0.B from ph2, buf0.A from ph4, buf1.B from ph6, buf1.A ph8.
//
// Stage slots (all strictly after target's last read + barrier):
//   ph1: T+1.A1   ph2: T+2.B0   ph3: T+2.B1   ph4: T+2.A0 + vm6
//   ph5: T+2.A1   ph6: T+3.B0   ph7: T+3.B1   ph8: T+3.A0 + vm6
// vmcnt ledger (2 loads/stage): at ph4-wait in-flight = 7 stages; retire
// through s1 (T+1.A1 -> ALL of tile T+1) leaves 3 stages = 6 loads -> vmcnt(6).
#define BM2 256
#define BN2 256
#define BK2 64
#define NT2 (K_TOT / BK2)      // 64 K-tiles
#define BUFB (256 * 128)       // LDS bytes per buffer (256 rows x 128B)

__global__ __launch_bounds__(512, 2) void gemm_kernel(float* __restrict__ out) {
  __shared__ unsigned short As[2][BM2][BK2];   // 64 KB
  __shared__ unsigned short Bs[2][BN2][BK2];   // 64 KB
  const int tid = threadIdx.x;
  const int lane = tid & 63;
  const int w = tid >> 6;            // 0..7
  const int wm = w >> 2, wn = w & 3;

  // XCD-aware swizzle: 1024 blocks, 8 XCDs, chunk = 128 (bijective, 1024%8==0)
  const int orig = blockIdx.x;
  const int swz = (orig & 7) * 128 + (orig >> 3);
  const int gm0 = (swz >> 4) * BM2;  // 64 M-tiles
  const int gn0 = (swz & 15) * BN2;  // 16 N-tiles

  f32x4 acc[8][4];
#pragma unroll
  for (int i = 0; i < 8; ++i)
#pragma unroll
    for (int j = 0; j < 4; ++j) acc[i][j] = (f32x4){0.f, 0.f, 0.f, 0.f};

  // ---- staging addressing (pre-swizzled global source, linear LDS dest) ----
  const int sr = (w << 3) + (lane >> 3);           // row 0..63 within a call
  const int sc = 8 * ((lane & 7) ^ (lane >> 3));   // swizzled source col (elems)
  const unsigned short* Agp = g_xb + (size_t)(gm0 + sr) * K_TOT + sc;
  const unsigned short* Bgp = g_wb + (size_t)(gn0 + sr) * K_TOT + sc;
  const int lr = (w << 3);                          // wave-uniform LDS row base

#define STAGE_A(tile, half) do {                                             \
    const int bi_ = (tile) & 1; const int kb_ = ((tile) & (NT2 - 1)) * BK2;  \
    __builtin_amdgcn_global_load_lds(                                        \
        (const AS1 void*)(Agp + (size_t)((half) * 128) * K_TOT + kb_),       \
        (AS3 void*)(&As[bi_][(half) * 128 + lr][0]), 16, 0, 0);              \
    __builtin_amdgcn_global_load_lds(                                        \
        (const AS1 void*)(Agp + (size_t)((half) * 128 + 64) * K_TOT + kb_),  \
        (AS3 void*)(&As[bi_][(half) * 128 + 64 + lr][0]), 16, 0, 0);         \
  } while (0)
#define STAGE_B(tile, half) do {                                             \
    const int bi_ = (tile) & 1; const int kb_ = ((tile) & (NT2 - 1)) * BK2;  \
    __builtin_amdgcn_global_load_lds(                                        \
        (const AS1 void*)(Bgp + (size_t)((half) * 128) * K_TOT + kb_),       \
        (AS3 void*)(&Bs[bi_][(half) * 128 + lr][0]), 16, 0, 0);              \
    __builtin_amdgcn_global_load_lds(                                        \
        (const AS1 void*)(Bgp + (size_t)((half) * 128 + 64) * K_TOT + kb_),  \
        (AS3 void*)(&Bs[bi_][(half) * 128 + 64 + lr][0]), 16, 0, 0);         \
  } while (0)

  // ---- fragment read addressing (XOR swizzle on byte column) ----
  const int r16 = lane & 15;
  const int kcb = (lane >> 4) << 4;        // 16B slot within 64B k-half
  const int xv = (r16 & 7) << 4;
  const char* Ab0 = (const char*)&As[0][wm * 128][0];
  const char* Bb0 = (const char*)&Bs[0][wn * 64][0];

  bf16x8 pA[4][2], pB0[2][2], pB1[2][2];

#define LD_A(qm, bi) do {                                                     \
    const char* ab_ = Ab0 + (bi) * BUFB + ((qm) * 64 + r16) * 128;            \
    _Pragma("unroll") for (int mi = 0; mi < 4; ++mi)                          \
      _Pragma("unroll") for (int sk = 0; sk < 2; ++sk)                        \
        pA[mi][sk] = *(const bf16x8*)(ab_ + mi * 16 * 128 +                   \
                                      ((sk * 64 + kcb) ^ xv));                \
  } while (0)
#define LD_B(P, qn, bi) do {                                                  \
    const char* bb_ = Bb0 + (bi) * BUFB + ((qn) * 32 + r16) * 128;            \
    _Pragma("unroll") for (int nf = 0; nf < 2; ++nf)                          \
      _Pragma("unroll") for (int sk = 0; sk < 2; ++sk)                        \
        P[nf][sk] = *(const bf16x8*)(bb_ + nf * 16 * 128 +                    \
                                     ((sk * 64 + kcb) ^ xv));                 \
  } while (0)
#define MFMA_Q(qm, qn, P) do {                                                \
    __builtin_amdgcn_s_setprio(1);                                            \
    _Pragma("unroll") for (int mi = 0; mi < 4; ++mi)                          \
      _Pragma("unroll") for (int nf = 0; nf < 2; ++nf)                        \
        _Pragma("unroll") for (int sk = 0; sk < 2; ++sk)                      \
          acc[(qm) * 4 + mi][(qn) * 2 + nf] =                                 \
              __builtin_amdgcn_mfma_f32_16x16x32_bf16(                        \
                  pA[mi][sk], P[nf][sk], acc[(qm) * 4 + mi][(qn) * 2 + nf],   \
                  0, 0, 0);                                                   \
    __builtin_amdgcn_s_setprio(0);                                            \
  } while (0)
#define BAR() __builtin_amdgcn_s_barrier()
#define WLG() asm volatile("s_waitcnt lgkmcnt(0)" ::: "memory")
#define WVM6() asm volatile("s_waitcnt vmcnt(6)" ::: "memory")

  // prologue: tile0 complete (4 stages), then T1.{B0,B1,A0} (3 stages);
  // vmcnt(6) retires exactly tile0 -> loop enters in steady-state invariant.
  STAGE_A(0, 0); STAGE_A(0, 1); STAGE_B(0, 0); STAGE_B(0, 1);
  STAGE_B(1, 0); STAGE_B(1, 1); STAGE_A(1, 0);
  WVM6();
  BAR();

  for (int it = 0; it < NT2 / 2; ++it) {
    const int T = 2 * it;
    // ---- K-tile T (buf0) ----
    // ph1: A-quad0 + both B halves (16 ds_reads)
    LD_A(0, 0); LD_B(pB0, 0, 0); LD_B(pB1, 1, 0);
    STAGE_A(T + 1, 1);
    BAR(); WLG();
    MFMA_Q(0, 0, pB0);
    BAR();
    // ph2: no ds_reads (pA, pB1 already live)
    STAGE_B(T + 2, 0);
    BAR();
    MFMA_Q(0, 1, pB1);
    BAR();
    // ph3: A-quad1 (8 ds_reads)
    LD_A(1, 0);
    STAGE_B(T + 2, 1);
    BAR(); WLG();
    MFMA_Q(1, 1, pB1);
    BAR();
    // ph4: vmcnt(6) after MFMA -> tile T+1 fully landed
    STAGE_A(T + 2, 0);
    BAR();
    MFMA_Q(1, 0, pB0);
    WVM6();
    BAR();
    // ---- K-tile T+1 (buf1) ----
    // ph5
    LD_A(0, 1); LD_B(pB0, 0, 1); LD_B(pB1, 1, 1);
    STAGE_A(T + 2, 1);
    BAR(); WLG();
    MFMA_Q(0, 0, pB0);
    BAR();
    // ph6
    STAGE_B(T + 3, 0);
    BAR();
    MFMA_Q(0, 1, pB1);
    BAR();
    // ph7
    LD_A(1, 1);
    STAGE_B(T + 3, 1);
    BAR(); WLG();
    MFMA_Q(1, 1, pB1);
    BAR();
    // ph8: vmcnt(6) -> tile T+2 fully landed
    STAGE_A(T + 3, 0);
    BAR();
    MFMA_Q(1, 0, pB0);
    WVM6();
    BAR();
  }

  // C/D layout (m89-verified): col = lane&15, row = (lane>>4)*4 + reg.
  const int cm0 = gm0 + wm * 128 + (lane >> 4) * 4;
  const int cn0 = gn0 + wn * 64 + (lane & 15);
#pragma unroll
  for (int mi = 0; mi < 8; ++mi)
#pragma unroll
    for (int nf = 0; nf < 4; ++nf)
#pragma unroll
      for (int r = 0; r < 4; ++r)
        out[(size_t)(cm0 + mi * 16 + r) * N_TOT + cn0 + nf * 16] = acc[mi][nf][r];
}

extern "C" void kernel_launch(void* const* d_in, const int* in_sizes, int n_in,
                              void* d_out, int out_size, void* d_ws, size_t ws_size,
                              hipStream_t stream) {
  const float* x  = (const float*)d_in[0];
  const float* wt = (const float*)d_in[1];
  const float* gr = (const float*)d_in[2];
  const void*  mk = d_in[3];
  const int*   nd = (const int*)d_in[4];
  (void)d_ws; (void)ws_size; (void)in_sizes; (void)n_in; (void)out_size;

  ctl_reset<<<1, 256, 0, stream>>>();
  mask_popcnt<<<512, 256, 0, stream>>>((const unsigned int*)mk);
  sel_init<<<1, 1, 0, stream>>>(nd);

  const int shifts[5] = {44, 32, 24, 12, 0};
  const int nbits[5]  = {12, 12, 8, 12, 12};

  // drop: k smallest |w| (global). Pass 1 full scan, then compact + 4 passes
  // over candidates only.
  hist_pass<0><<<1024, 256, 0, stream>>>(wt, shifts[0], nbits[0]);
  select_pass<0><<<1, 256, 0, stream>>>(shifts[0], nbits[0]);
  compact_pass<0><<<1024, 256, 0, stream>>>(wt);
  for (int p = 1; p < 5; ++p) {
    hist_cand<0><<<256, 256, 0, stream>>>(shifts[p], nbits[p]);
    select_pass<0><<<1, 256, 0, stream>>>(shifts[p], nbits[p]);
  }
  build_elig<<<NELEM / 4 / 256, 256, 0, stream>>>(wt, mk);
  // grow: k largest |grad| among eligible.
  hist_pass<1><<<1024, 256, 0, stream>>>(gr, shifts[0], nbits[0]);
  select_pass<1><<<1, 256, 0, stream>>>(shifts[0], nbits[0]);
  compact_pass<1><<<1024, 256, 0, stream>>>(gr);
  for (int p = 1; p < 5; ++p) {
    hist_cand<1><<<256, 256, 0, stream>>>(shifts[p], nbits[p]);
    select_pass<1><<<1, 256, 0, stream>>>(shifts[p], nbits[p]);
  }
  build_wb<<<NELEM / 4 / 256, 256, 0, stream>>>(wt, gr);
  convert_x<<<(M_TOT * K_TOT / 4) / 256, 256, 0, stream>>>(x);
  gemm_kernel<<<1024, 512, 0, stream>>>((float*)d_out);
}

// Round 7
// 882.178 us; speedup vs baseline: 2.2815x; 1.1462x over previous
//
#include <hip/hip_runtime.h>
#include <hip/hip_bf16.h>

// Problem constants (fixed by the reference): B=8, S=2048, IN=4096, OUT=4096
#define M_TOT 16384
#define N_TOT 4096
#define K_TOT 4096
#define NELEM 16777216   // OUT*IN = 2^24 (index fits in 24 bits)

typedef __attribute__((ext_vector_type(8))) short bf16x8;
typedef __attribute__((ext_vector_type(4))) float f32x4;

#define AS1 __attribute__((address_space(1)))
#define AS3 __attribute__((address_space(3)))

struct SelState {
  unsigned long long prefix;   // accumulated high key bits
  unsigned long long thr;      // selection predicate: key <= thr
  unsigned int k_rem;
  unsigned int done;
  unsigned int active;
};

struct Ctl {
  unsigned long long pcount;   // mask popcount for dtype detection
  unsigned int mask_is_byte;
  unsigned int cand_n;         // compacted candidate count
  SelState d;                  // drop selection state
  SelState g;                  // grow selection state
};

__device__ Ctl g_ctl;
__device__ unsigned int g_hist[4096];
__device__ unsigned char g_elig[NELEM];          // 1 = slot OFF after drop (grow candidate)
__device__ unsigned short g_wb[NELEM];           // masked weight, bf16 bits [OUT][IN]
__device__ unsigned short g_xb[(size_t)M_TOT * K_TOT]; // x, bf16 bits [M][K]
__device__ unsigned long long g_cand[NELEM];     // compacted keys after radix pass 1

__device__ __forceinline__ unsigned short f2bf(float f) {
  unsigned int u = __float_as_uint(f);
  unsigned int r = (u + 0x7FFFu + ((u >> 16) & 1u)) >> 16;   // RNE
  return (unsigned short)r;
}

// 56-bit keys. Nonnegative floats: bit pattern order == value order.
__device__ __forceinline__ unsigned long long key_drop_bits(unsigned int fb, int i) {
  unsigned int b = fb & 0x7FFFFFFFu;
  return (((unsigned long long)b) << 24) | (unsigned int)i;   // smallest |w|, lowest idx first
}
__device__ __forceinline__ unsigned long long key_grow_bits(unsigned int fb, int i) {
  unsigned int b = ~(fb & 0x7FFFFFFFu);                       // descending |grad|
  return (((unsigned long long)b) << 24) | (unsigned int)i;   // largest |g|, lowest idx first
}

__global__ void ctl_reset() {
  int t = threadIdx.x;
  if (t == 0) { g_ctl.pcount = 0ull; g_ctl.cand_n = 0u; }
  for (int i = t; i < 4096; i += 256) g_hist[i] = 0;
}

// Detect mask dtype: read first NELEM bytes as u32 words (safe under both
// interpretations). bytes(bool): popcnt ~= 2.18M ; int32: popcnt ~= 545K.
__global__ void mask_popcnt(const unsigned int* mw) {
  const int NW = NELEM / 4;
  unsigned int s = 0;
  for (int i = blockIdx.x * blockDim.x + threadIdx.x; i < NW; i += gridDim.x * blockDim.x)
    s += __popc(mw[i]);
  for (int off = 32; off > 0; off >>= 1) s += __shfl_down(s, off, 64);
  if ((threadIdx.x & 63) == 0)
    atomicAdd((unsigned long long*)&g_ctl.pcount, (unsigned long long)s);
}

__global__ void sel_init(const int* ndp) {
  unsigned int k = (unsigned int)ndp[0];
  g_ctl.mask_is_byte = (g_ctl.pcount > 1200000ull) ? 1u : 0u;
  SelState s;
  s.prefix = 0ull; s.thr = 0ull; s.k_rem = k;
  s.done = (k == 0u) ? 1u : 0u;
  s.active = (k > 0u) ? 1u : 0u;
  g_ctl.d = s;
  g_ctl.g = s;
}

// Histogram of key bit-slice [shift, shift+nbits) over the FULL array (pass 1).
template <int SEL>
__global__ __launch_bounds__(256) void hist_pass(const float* __restrict__ src, int shift, int nbits) {
  SelState& st = SEL ? g_ctl.g : g_ctl.d;
  if (st.done) return;
  __shared__ unsigned int lh[4096];
  const int nb = 1 << nbits;
  for (int i = threadIdx.x; i < nb; i += blockDim.x) lh[i] = 0;
  __syncthreads();
  const unsigned long long pref = st.prefix;
  const int N4 = NELEM / 4;
  for (int q = blockIdx.x * blockDim.x + threadIdx.x; q < N4; q += gridDim.x * blockDim.x) {
    float4 v = ((const float4*)src)[q];
    float fv[4] = {v.x, v.y, v.z, v.w};
    unsigned char ev[4] = {1, 1, 1, 1};
    if (SEL) {
      uchar4 e4 = ((const uchar4*)g_elig)[q];
      ev[0] = e4.x; ev[1] = e4.y; ev[2] = e4.z; ev[3] = e4.w;
    }
#pragma unroll
    for (int j = 0; j < 4; ++j) {
      if (SEL && !ev[j]) continue;
      int i = q * 4 + j;
      unsigned int fb = __float_as_uint(fv[j]);
      unsigned long long key = SEL ? key_grow_bits(fb, i) : key_drop_bits(fb, i);
      if ((key >> (shift + nbits)) == pref)
        atomicAdd(&lh[(unsigned int)(key >> shift) & (unsigned int)(nb - 1)], 1u);
    }
  }
  __syncthreads();
  for (int i = threadIdx.x; i < nb; i += blockDim.x)
    if (lh[i]) atomicAdd(&g_hist[i], lh[i]);
}

// After pass 1: compact keys matching the selected 12-bit prefix.
// Hierarchical append (G12): matches -> per-block LDS buffer (LDS atomics),
// then ONE global atomicAdd per block reserves a contiguous range, coalesced
// copy-out. Overflow fallback (cold) keeps the multiset exact.
#define CCAP 4096
template <int SEL>
__global__ __launch_bounds__(256) void compact_pass(const float* __restrict__ src) {
  SelState& st = SEL ? g_ctl.g : g_ctl.d;
  if (st.done) return;
  __shared__ unsigned long long lk[CCAP];   // 32 KB
  __shared__ unsigned int ln;
  __shared__ unsigned int gbase;
  if (threadIdx.x == 0) ln = 0;
  __syncthreads();
  const unsigned long long pref = st.prefix;   // 12 bits after pass 1
  const int N4 = NELEM / 4;
  for (int q = blockIdx.x * blockDim.x + threadIdx.x; q < N4; q += gridDim.x * blockDim.x) {
    float4 v = ((const float4*)src)[q];
    float fv[4] = {v.x, v.y, v.z, v.w};
    unsigned char ev[4] = {1, 1, 1, 1};
    if (SEL) {
      uchar4 e4 = ((const uchar4*)g_elig)[q];
      ev[0] = e4.x; ev[1] = e4.y; ev[2] = e4.z; ev[3] = e4.w;
    }
#pragma unroll
    for (int j = 0; j < 4; ++j) {
      if (SEL && !ev[j]) continue;
      int i = q * 4 + j;
      unsigned int fb = __float_as_uint(fv[j]);
      unsigned long long key = SEL ? key_grow_bits(fb, i) : key_drop_bits(fb, i);
      if ((key >> 44) == pref) {
        unsigned int slot = atomicAdd(&ln, 1u);
        if (slot < CCAP) {
          lk[slot] = key;
        } else {                               // overflow fallback (cold)
          unsigned int gb = atomicAdd(&g_ctl.cand_n, 1u);
          g_cand[gb] = key;
        }
      }
    }
  }
  __syncthreads();
  unsigned int n = ln < CCAP ? ln : CCAP;
  if (threadIdx.x == 0) gbase = atomicAdd(&g_ctl.cand_n, n);
  __syncthreads();
  for (unsigned int i = threadIdx.x; i < n; i += blockDim.x)
    g_cand[gbase + i] = lk[i];
}

// Passes 2..5: histogram over compacted candidates only.
template <int SEL>
__global__ __launch_bounds__(256) void hist_cand(int shift, int nbits) {
  SelState& st = SEL ? g_ctl.g : g_ctl.d;
  if (st.done) return;
  __shared__ unsigned int lh[4096];
  const int nb = 1 << nbits;
  for (int i = threadIdx.x; i < nb; i += blockDim.x) lh[i] = 0;
  __syncthreads();
  const unsigned long long pref = st.prefix;
  const unsigned int n = g_ctl.cand_n;
  for (unsigned int i = blockIdx.x * blockDim.x + threadIdx.x; i < n; i += gridDim.x * blockDim.x) {
    unsigned long long key = g_cand[i];
    if ((key >> (shift + nbits)) == pref)
      atomicAdd(&lh[(unsigned int)(key >> shift) & (unsigned int)(nb - 1)], 1u);
  }
  __syncthreads();
  for (int i = threadIdx.x; i < nb; i += blockDim.x)
    if (lh[i]) atomicAdd(&g_hist[i], lh[i]);
}

// Single-block: find the bin containing the k_rem-th element, update state,
// zero the histogram for the next pass.
template <int SEL>
__global__ void select_pass(int shift, int nbits) {
  SelState& st = SEL ? g_ctl.g : g_ctl.d;
  if (st.done) return;   // hist untouched (stays zero) when done
  __shared__ unsigned int sc[256];
  __shared__ int tgt;
  const int nb = 1 << nbits;
  const int per = (nb + 255) / 256;
  const int t = threadIdx.x;
  unsigned int s = 0;
  for (int j = 0; j < per; ++j) {
    int b = t * per + j;
    if (b < nb) s += g_hist[b];
  }
  sc[t] = s;
  __syncthreads();
  for (int off = 1; off < 256; off <<= 1) {   // inclusive scan
    unsigned int v = (t >= off) ? sc[t - off] : 0u;
    __syncthreads();
    sc[t] += v;
    __syncthreads();
  }
  const unsigned int k = st.k_rem;
  const unsigned int cum = sc[t];
  const unsigned int before = cum - s;
  if (before < k && k <= cum) tgt = t;   // exactly one thread matches
  __syncthreads();
  if (t == tgt) {
    unsigned int c = before;
    for (int j = 0; j < per; ++j) {
      int b = t * per + j;
      unsigned int h = (b < nb) ? g_hist[b] : 0u;
      if (c + h >= k) {
        unsigned long long np = (st.prefix << nbits) | (unsigned long long)(unsigned int)b;
        st.prefix = np;
        st.k_rem = k - c;
        st.thr = ((np + 1ull) << shift) - 1ull;   // all keys with this prefix or less
        if (k - c == h) st.done = 1;              // k-th is the max of this bin: exact
        break;
      }
      c += h;
    }
  }
  __syncthreads();
  for (int b = t; b < nb; b += 256) g_hist[b] = 0;
}

// eligible (grow candidate) = slot OFF after drop = !mask || dropped. 4/thread.
// Also resets cand_n for the grow-phase compaction (stream-ordered).
__global__ __launch_bounds__(256) void build_elig(const float* __restrict__ w, const void* maskp) {
  if (blockIdx.x == 0 && threadIdx.x == 0) g_ctl.cand_n = 0u;
  int q = blockIdx.x * blockDim.x + threadIdx.x;   // over quads
  if (q >= NELEM / 4) return;
  float4 wv = ((const float4*)w)[q];
  float fv[4] = {wv.x, wv.y, wv.z, wv.w};
  unsigned char m[4];
  if (g_ctl.mask_is_byte) {
    uchar4 m4 = ((const uchar4*)maskp)[q];
    m[0] = m4.x; m[1] = m4.y; m[2] = m4.z; m[3] = m4.w;
  } else {
    int4 m4 = ((const int4*)maskp)[q];
    m[0] = m4.x != 0; m[1] = m4.y != 0; m[2] = m4.z != 0; m[3] = m4.w != 0;
  }
  const bool act = g_ctl.d.active;
  const unsigned long long thr = g_ctl.d.thr;
  uchar4 e;
  unsigned char ev[4];
#pragma unroll
  for (int j = 0; j < 4; ++j) {
    int i = q * 4 + j;
    bool dropped = act && (key_drop_bits(__float_as_uint(fv[j]), i) <= thr);
    ev[j] = (!m[j] || dropped) ? 1 : 0;
  }
  e.x = ev[0]; e.y = ev[1]; e.z = ev[2]; e.w = ev[3];
  ((uchar4*)g_elig)[q] = e;
}

// final mask: kept (= !elig) OR grown (elig && grow-key selected); emit bf16 W
__global__ __launch_bounds__(256) void build_wb(const float* __restrict__ w, const float* __restrict__ gr) {
  int q = blockIdx.x * blockDim.x + threadIdx.x;
  if (q >= NELEM / 4) return;
  float4 wv = ((const float4*)w)[q];
  float4 gv = ((const float4*)gr)[q];
  float wf[4] = {wv.x, wv.y, wv.z, wv.w};
  float gf[4] = {gv.x, gv.y, gv.z, gv.w};
  uchar4 e4 = ((const uchar4*)g_elig)[q];
  unsigned char ev[4] = {e4.x, e4.y, e4.z, e4.w};
  const bool act = g_ctl.g.active;
  const unsigned long long thr = g_ctl.g.thr;
  ushort4 o;
  unsigned short ov[4];
#pragma unroll
  for (int j = 0; j < 4; ++j) {
    int i = q * 4 + j;
    bool keep;
    if (!ev[j]) keep = true;
    else keep = act && (key_grow_bits(__float_as_uint(gf[j]), i) <= thr);
    ov[j] = keep ? f2bf(wf[j]) : (unsigned short)0;
  }
  o.x = ov[0]; o.y = ov[1]; o.z = ov[2]; o.w = ov[3];
  ((ushort4*)g_wb)[q] = o;
}

__global__ __launch_bounds__(256) void convert_x(const float* __restrict__ x) {
  int i = blockIdx.x * blockDim.x + threadIdx.x;   // over float4 quads
  float4 v = ((const float4*)x)[i];
  ushort4 o;
  o.x = f2bf(v.x); o.y = f2bf(v.y); o.z = f2bf(v.z); o.w = f2bf(v.w);
  ((ushort4*)g_xb)[i] = o;
}

// ---- GEMM: C[m][n] = sum_k X[m][k] * W[n][k], bf16 in, fp32 out ----
// 256x256 tile, BK=64, 512 threads = 8 waves (2M x 4N), per-wave 128x64 out.
// Round-7 changes vs round 6 (stage slots and vmcnt ledger UNCHANGED):
//  (a) m201-exact read spread: ph1 = A-quad0 + B-half0 (12 ds_reads,
//      + lgkmcnt(8) hint); ph2 = B-half1 (4); ph3 = A-quad1 (8); ph4 = 0.
//      (Round 6 bunched 16 reads in ph1 -> all-wave lgkmcnt(0) drain.)
//      Hazard-safe: pB1's read moves LATER (ph1->ph2); its buffer region is
//      overwritten at ph3's stage, still >=1 barrier after the read.
//  (b) LDS-bounce coalesced epilogue: acc -> LDS (stride 260 floats -> 2-way
//      bank aliasing = free), then one 256-float row per wave per float4
//      store (1KB/instr, fully coalesced). 4 quarter-rounds of 64 rows
//      (66.5KB <= 128KB), reusing the (dead) tile LDS after the K-loop.
//
// Stage slots (unchanged):
//   ph1: T+1.A1   ph2: T+2.B0   ph3: T+2.B1   ph4: T+2.A0 + vm6
//   ph5: T+2.A1   ph6: T+3.B0   ph7: T+3.B1   ph8: T+3.A0 + vm6
// vmcnt(6)@ph4 retires tile T+1 fully; @ph8 retires T+2. Per-tile last
// reads: B-half0 ph1, B-half1 ph2, A ph3 -> every stage slot lands >=1
// barrier after its target's last read.
#define BM2 256
#define BN2 256
#define BK2 64
#define NT2 (K_TOT / BK2)      // 64 K-tiles
#define BUFB (256 * 128)       // LDS bytes per buffer (256 rows x 128B)

__global__ __launch_bounds__(512, 2) void gemm_kernel(float* __restrict__ out) {
  __shared__ __align__(16) char smem[131072];    // [A: 64KB][B: 64KB] / epilogue f32
  unsigned short* Asb = (unsigned short*)smem;             // [2][256][64]
  unsigned short* Bsb = (unsigned short*)(smem + 65536);   // [2][256][64]
  const int tid = threadIdx.x;
  const int lane = tid & 63;
  const int w = tid >> 6;            // 0..7
  const int wm = w >> 2, wn = w & 3;

  // XCD-aware swizzle: 1024 blocks, 8 XCDs, chunk = 128 (bijective, 1024%8==0)
  const int orig = blockIdx.x;
  const int swz = (orig & 7) * 128 + (orig >> 3);
  const int gm0 = (swz >> 4) * BM2;  // 64 M-tiles
  const int gn0 = (swz & 15) * BN2;  // 16 N-tiles

  f32x4 acc[8][4];
#pragma unroll
  for (int i = 0; i < 8; ++i)
#pragma unroll
    for (int j = 0; j < 4; ++j) acc[i][j] = (f32x4){0.f, 0.f, 0.f, 0.f};

  // ---- staging addressing (pre-swizzled global source, linear LDS dest) ----
  const int sr = (w << 3) + (lane >> 3);           // row 0..63 within a call
  const int sc = 8 * ((lane & 7) ^ (lane >> 3));   // swizzled source col (elems)
  const unsigned short* Agp = g_xb + (size_t)(gm0 + sr) * K_TOT + sc;
  const unsigned short* Bgp = g_wb + (size_t)(gn0 + sr) * K_TOT + sc;
  const int lr = (w << 3);                          // wave-uniform LDS row base

#define STAGE_A(tile, half) do {                                             \
    const int bi_ = (tile) & 1; const int kb_ = ((tile) & (NT2 - 1)) * BK2;  \
    __builtin_amdgcn_global_load_lds(                                        \
        (const AS1 void*)(Agp + (size_t)((half) * 128) * K_TOT + kb_),       \
        (AS3 void*)(Asb + (size_t)bi_ * (BM2 * BK2) +                        \
                    ((half) * 128 + lr) * BK2), 16, 0, 0);                   \
    __builtin_amdgcn_global_load_lds(                                        \
        (const AS1 void*)(Agp + (size_t)((half) * 128 + 64) * K_TOT + kb_),  \
        (AS3 void*)(Asb + (size_t)bi_ * (BM2 * BK2) +                        \
                    ((half) * 128 + 64 + lr) * BK2), 16, 0, 0);              \
  } while (0)
#define STAGE_B(tile, half) do {                                             \
    const int bi_ = (tile) & 1; const int kb_ = ((tile) & (NT2 - 1)) * BK2;  \
    __builtin_amdgcn_global_load_lds(                                        \
        (const AS1 void*)(Bgp + (size_t)((half) * 128) * K_TOT + kb_),       \
        (AS3 void*)(Bsb + (size_t)bi_ * (BN2 * BK2) +                        \
                    ((half) * 128 + lr) * BK2), 16, 0, 0);                   \
    __builtin_amdgcn_global_load_lds(                                        \
        (const AS1 void*)(Bgp + (size_t)((half) * 128 + 64) * K_TOT + kb_),  \
        (AS3 void*)(Bsb + (size_t)bi_ * (BN2 * BK2) +                        \
                    ((half) * 128 + 64 + lr) * BK2), 16, 0, 0);              \
  } while (0)

  // ---- fragment read addressing (XOR swizzle on byte column) ----
  const int r16 = lane & 15;
  const int kcb = (lane >> 4) << 4;        // 16B slot within 64B k-half
  const int xv = (r16 & 7) << 4;
  const char* Ab0 = (const char*)(Asb + wm * 128 * BK2);
  const char* Bb0 = (const char*)(Bsb + wn * 64 * BK2);

  bf16x8 pA[4][2], pB0[2][2], pB1[2][2];

#define LD_A(qm, bi) do {                                                     \
    const char* ab_ = Ab0 + (bi) * BUFB + ((qm) * 64 + r16) * 128;            \
    _Pragma("unroll") for (int mi = 0; mi < 4; ++mi)                          \
      _Pragma("unroll") for (int sk = 0; sk < 2; ++sk)                        \
        pA[mi][sk] = *(const bf16x8*)(ab_ + mi * 16 * 128 +                   \
                                      ((sk * 64 + kcb) ^ xv));                \
  } while (0)
#define LD_B(P, qn, bi) do {                                                  \
    const char* bb_ = Bb0 + (bi) * BUFB + ((qn) * 32 + r16) * 128;            \
    _Pragma("unroll") for (int nf = 0; nf < 2; ++nf)                          \
      _Pragma("unroll") for (int sk = 0; sk < 2; ++sk)                        \
        P[nf][sk] = *(const bf16x8*)(bb_ + nf * 16 * 128 +                    \
                                     ((sk * 64 + kcb) ^ xv));                 \
  } while (0)
#define MFMA_Q(qm, qn, P) do {                                                \
    __builtin_amdgcn_s_setprio(1);                                            \
    _Pragma("unroll") for (int mi = 0; mi < 4; ++mi)                          \
      _Pragma("unroll") for (int nf = 0; nf < 2; ++nf)                        \
        _Pragma("unroll") for (int sk = 0; sk < 2; ++sk)                      \
          acc[(qm) * 4 + mi][(qn) * 2 + nf] =                                 \
              __builtin_amdgcn_mfma_f32_16x16x32_bf16(                        \
                  pA[mi][sk], P[nf][sk], acc[(qm) * 4 + mi][(qn) * 2 + nf],   \
                  0, 0, 0);                                                   \
    __builtin_amdgcn_s_setprio(0);                                            \
  } while (0)
#define BAR() __builtin_amdgcn_s_barrier()
#define WLG() asm volatile("s_waitcnt lgkmcnt(0)" ::: "memory")
#define WLG8() asm volatile("s_waitcnt lgkmcnt(8)" ::: "memory")
#define WVM6() asm volatile("s_waitcnt vmcnt(6)" ::: "memory")

  // prologue: tile0 complete (4 stages), then T1.{B0,B1,A0} (3 stages);
  // vmcnt(6) retires exactly tile0 -> loop enters in steady-state invariant.
  STAGE_A(0, 0); STAGE_A(0, 1); STAGE_B(0, 0); STAGE_B(0, 1);
  STAGE_B(1, 0); STAGE_B(1, 1); STAGE_A(1, 0);
  WVM6();
  BAR();

  for (int it = 0; it < NT2 / 2; ++it) {
    const int T = 2 * it;
    // ---- K-tile T (buf0) ----
    // ph1: A-quad0 + B-half0 (12 ds_reads, lgkmcnt(8) hint)
    LD_A(0, 0); LD_B(pB0, 0, 0);
    STAGE_A(T + 1, 1);
    WLG8();
    BAR(); WLG();
    MFMA_Q(0, 0, pB0);
    BAR();
    // ph2: B-half1 (4 ds_reads)
    LD_B(pB1, 1, 0);
    STAGE_B(T + 2, 0);
    BAR(); WLG();
    MFMA_Q(0, 1, pB1);
    BAR();
    // ph3: A-quad1 (8 ds_reads)
    LD_A(1, 0);
    STAGE_B(T + 2, 1);
    BAR(); WLG();
    MFMA_Q(1, 1, pB1);
    BAR();
    // ph4: vmcnt(6) after MFMA -> tile T+1 fully landed
    STAGE_A(T + 2, 0);
    BAR();
    MFMA_Q(1, 0, pB0);
    WVM6();
    BAR();
    // ---- K-tile T+1 (buf1) ----
    // ph5
    LD_A(0, 1); LD_B(pB0, 0, 1);
    STAGE_A(T + 2, 1);
    WLG8();
    BAR(); WLG();
    MFMA_Q(0, 0, pB0);
    BAR();
    // ph6
    LD_B(pB1, 1, 1);
    STAGE_B(T + 3, 0);
    BAR(); WLG();
    MFMA_Q(0, 1, pB1);
    BAR();
    // ph7
    LD_A(1, 1);
    STAGE_B(T + 3, 1);
    BAR(); WLG();
    MFMA_Q(1, 1, pB1);
    BAR();
    // ph8: vmcnt(6) -> tile T+2 fully landed
    STAGE_A(T + 3, 0);
    BAR();
    MFMA_Q(1, 0, pB0);
    WVM6();
    BAR();
  }

  // ---- coalesced epilogue via LDS bounce ----
  // C/D frag layout (m89-verified): col = lane&15, row = (lane>>4)*4 + reg.
  // 4 quarter-rounds; quarter Q covers mi in {2Q, 2Q+1} of both wm groups
  // = 64 rows. LDS stride 260 floats: acc-write rows {0,4,8,12}+b alias
  // 2-way (free, m136); wave-store reads one full row per float4 instr.
  float* lf = (float*)smem;
#pragma unroll
  for (int Q = 0; Q < 4; ++Q) {
    __syncthreads();
#pragma unroll
    for (int m2 = 0; m2 < 2; ++m2) {
      const int rl0 = (wm * 2 + m2) * 16 + (lane >> 4) * 4;
#pragma unroll
      for (int nf = 0; nf < 4; ++nf) {
        const int col = wn * 64 + nf * 16 + (lane & 15);
#pragma unroll
        for (int r = 0; r < 4; ++r)
          lf[(rl0 + r) * 260 + col] = acc[Q * 2 + m2][nf][r];
      }
    }
    __syncthreads();
#pragma unroll
    for (int i2 = 0; i2 < 8; ++i2) {
      const int rl = w * 8 + i2;
      const int grow = (rl >> 5) * 128 + (Q * 2 + ((rl >> 4) & 1)) * 16 + (rl & 15);
      *(float4*)&out[(size_t)(gm0 + grow) * N_TOT + gn0 + lane * 4] =
          *(const float4*)&lf[rl * 260 + lane * 4];
    }
  }
}

extern "C" void kernel_launch(void* const* d_in, const int* in_sizes, int n_in,
                              void* d_out, int out_size, void* d_ws, size_t ws_size,
                              hipStream_t stream) {
  const float* x  = (const float*)d_in[0];
  const float* wt = (const float*)d_in[1];
  const float* gr = (const float*)d_in[2];
  const void*  mk = d_in[3];
  const int*   nd = (const int*)d_in[4];
  (void)d_ws; (void)ws_size; (void)in_sizes; (void)n_in; (void)out_size;

  ctl_reset<<<1, 256, 0, stream>>>();
  mask_popcnt<<<512, 256, 0, stream>>>((const unsigned int*)mk);
  sel_init<<<1, 1, 0, stream>>>(nd);

  const int shifts[5] = {44, 32, 24, 12, 0};
  const int nbits[5]  = {12, 12, 8, 12, 12};

  // drop: k smallest |w| (global). Pass 1 full scan, then compact + 4 passes
  // over candidates only.
  hist_pass<0><<<1024, 256, 0, stream>>>(wt, shifts[0], nbits[0]);
  select_pass<0><<<1, 256, 0, stream>>>(shifts[0], nbits[0]);
  compact_pass<0><<<1024, 256, 0, stream>>>(wt);
  for (int p = 1; p < 5; ++p) {
    hist_cand<0><<<256, 256, 0, stream>>>(shifts[p], nbits[p]);
    select_pass<0><<<1, 256, 0, stream>>>(shifts[p], nbits[p]);
  }
  build_elig<<<NELEM / 4 / 256, 256, 0, stream>>>(wt, mk);
  // grow: k largest |grad| among eligible.
  hist_pass<1><<<1024, 256, 0, stream>>>(gr, shifts[0], nbits[0]);
  select_pass<1><<<1, 256, 0, stream>>>(shifts[0], nbits[0]);
  compact_pass<1><<<1024, 256, 0, stream>>>(gr);
  for (int p = 1; p < 5; ++p) {
    hist_cand<1><<<256, 256, 0, stream>>>(shifts[p], nbits[p]);
    select_pass<1><<<1, 256, 0, stream>>>(shifts[p], nbits[p]);
  }
  build_wb<<<NELEM / 4 / 256, 256, 0, stream>>>(wt, gr);
  convert_x<<<(M_TOT * K_TOT / 4) / 256, 256, 0, stream>>>(x);
  gemm_kernel<<<1024, 512, 0, stream>>>((float*)d_out);
}